// Round 1
// baseline (397.077 us; speedup 1.0000x reference)
//
#include <hip/hip_runtime.h>
#include <hip/hip_bf16.h>
#include <cstdint>

typedef float f32x4 __attribute__((ext_vector_type(4)));
typedef short bf16x8 __attribute__((ext_vector_type(8)));

__device__ __forceinline__ unsigned short f32_to_bf16_rne(float f) {
  unsigned int u = __float_as_uint(f);
  return (unsigned short)((u + 0x7FFFu + ((u >> 16) & 1u)) >> 16);
}

#define GLOAD_LDS16(gptr, lptr)                                                             \
  __builtin_amdgcn_global_load_lds((const __attribute__((address_space(1))) unsigned int*)(gptr), \
                                   (__attribute__((address_space(3))) unsigned int*)(lptr), 16, 0, 0)

// ---------------- f32 -> bf16 (8 elems / thread) ----------------
__global__ __launch_bounds__(256) void cvt_f32_to_bf16(const float* __restrict__ src,
                                                       unsigned short* __restrict__ dst,
                                                       int n8) {
  int i = blockIdx.x * 256 + threadIdx.x;
  if (i >= n8) return;
  const float4* s = (const float4*)src;
  float4 a = s[2 * i], b = s[2 * i + 1];
  uint4 o;
  o.x = (unsigned)f32_to_bf16_rne(a.x) | ((unsigned)f32_to_bf16_rne(a.y) << 16);
  o.y = (unsigned)f32_to_bf16_rne(a.z) | ((unsigned)f32_to_bf16_rne(a.w) << 16);
  o.z = (unsigned)f32_to_bf16_rne(b.x) | ((unsigned)f32_to_bf16_rne(b.y) << 16);
  o.w = (unsigned)f32_to_bf16_rne(b.z) | ((unsigned)f32_to_bf16_rne(b.w) << 16);
  ((uint4*)dst)[i] = o;
}

// ---------------- fuzzy membership + softmax over rules ----------------
// q: (M=2048, E=1024) f32 (already scaled); rk/rw: (H=16, R=32, D=64); attn out: (M, H, R)
__global__ __launch_bounds__(256) void fuzzy_softmax_k(const float* __restrict__ qf,
                                                       const float* __restrict__ rk,
                                                       const float* __restrict__ rw,
                                                       float* __restrict__ attn) {
  int p = blockIdx.x * 8 + (threadIdx.x >> 5);  // (m,h) pair index, 0..32767
  int r = threadIdx.x & 31;
  int m = p >> 4;
  int h = p & 15;
  const float* qrow = qf + (size_t)m * 1024 + h * 64;
  const float* krow = rk + (size_t)(h * 32 + r) * 64;
  const float* wrow = rw + (size_t)(h * 32 + r) * 64;
  float acc = 0.f;
#pragma unroll
  for (int d0 = 0; d0 < 64; d0 += 4) {
    float4 qv = *(const float4*)(qrow + d0);
    float4 kv = *(const float4*)(krow + d0);
    float4 wv = *(const float4*)(wrow + d0);
    float t;
    t = fabsf(qv.x - kv.x) / wv.x; acc += t * t;
    t = fabsf(qv.y - kv.y) / wv.y; acc += t * t;
    t = fabsf(qv.z - kv.z) / wv.z; acc += t * t;
    t = fabsf(qv.w - kv.w) / wv.w; acc += t * t;
  }
  float z = -0.5f * (acc * (1.0f / 64.0f));
  // softmax over 32 rules; lanes [0..31] and [32..63] are independent groups (masks<32 stay inside)
  float mx = z;
#pragma unroll
  for (int mask = 16; mask >= 1; mask >>= 1) mx = fmaxf(mx, __shfl_xor(mx, mask));
  float e = __expf(z - mx);
  float s = e;
#pragma unroll
  for (int mask = 16; mask >= 1; mask >>= 1) s += __shfl_xor(s, mask);
  attn[(size_t)m * 512 + h * 32 + r] = e / s;
}

// ---------------- bf16 GEMM: C[M,N] = A[M,K] @ W[N,K]^T, epilogue by MODE ----------------
// MODE 0: Cf = (acc + bias[n]) * scale                       (f32 out)
// MODE 1: fused rule aggregation:
//         X[b,h,s,d] = scale * sum_{r=0..31} attn[m,h,r] * (acc[m, h*2048+d*32+r] + bias[...])
//         X is bf16, laid out (B=2, H=16, S=1024, D=64) == row-major (B*S, E) for GEMM3.
// MODE 2: Cf = (acc + bias[n]) * scale                       (f32 out, scale=1)
template <int MODE>
__global__ __launch_bounds__(256) void gemm_bt(const unsigned short* __restrict__ A,
                                               const unsigned short* __restrict__ W,
                                               const float* __restrict__ bias, float scale,
                                               int M, int N, int K, float* __restrict__ Cf,
                                               const float* __restrict__ attn,
                                               unsigned short* __restrict__ X) {
  constexpr int BM = 128, BN = 128, BK = 32;
  __shared__ unsigned short As[2][BM * BK];
  __shared__ unsigned short Bs[2][BN * BK];
  const int tid = threadIdx.x;
  const int wid = tid >> 6;
  const int lane = tid & 63;
  const int l15 = lane & 15;
  const int l4 = lane >> 4;
  const int bm = blockIdx.y * BM;
  const int bn = blockIdx.x * BN;
  const int wr = (wid >> 1) * 64;  // wave row offset in tile
  const int wc = (wid & 1) * 64;   // wave col offset in tile

  f32x4 acc[4][4];
#pragma unroll
  for (int i = 0; i < 4; ++i)
#pragma unroll
    for (int j = 0; j < 4; ++j) acc[i][j] = (f32x4){0.f, 0.f, 0.f, 0.f};

  const int nk = K / BK;

  // Stage one BM x BK tile of A and BN x BK of W into LDS buffer `buf`.
  // Tile is row-major [rows][BK]; 16B chunk c -> row = c>>2, elem = (c&3)*8.
  // Each wave issues 2 chunks-of-64-lanes for A and 2 for B (8KB + 8KB total).
  auto stage = [&](int buf, int kt) {
#pragma unroll
    for (int i = 0; i < 2; ++i) {
      int c = (wid * 2 + i) * 64 + lane;
      const unsigned short* ga = A + (size_t)(bm + (c >> 2)) * K + kt * BK + (c & 3) * 8;
      GLOAD_LDS16(ga, &As[buf][(wid * 2 + i) * 512]);
      const unsigned short* gb = W + (size_t)(bn + (c >> 2)) * K + kt * BK + (c & 3) * 8;
      GLOAD_LDS16(gb, &Bs[buf][(wid * 2 + i) * 512]);
    }
  };

  stage(0, 0);
  __syncthreads();  // drains vmcnt

  for (int kt = 0; kt < nk; ++kt) {
    const int cur = kt & 1;
    if (kt + 1 < nk) stage(cur ^ 1, kt + 1);
    bf16x8 a[4], b[4];
    const int koff = l4 * 8;
#pragma unroll
    for (int mi = 0; mi < 4; ++mi)
      a[mi] = *(const bf16x8*)&As[cur][(wr + mi * 16 + l15) * BK + koff];
#pragma unroll
    for (int ni = 0; ni < 4; ++ni)
      b[ni] = *(const bf16x8*)&Bs[cur][(wc + ni * 16 + l15) * BK + koff];
#pragma unroll
    for (int mi = 0; mi < 4; ++mi)
#pragma unroll
      for (int ni = 0; ni < 4; ++ni)
        acc[mi][ni] = __builtin_amdgcn_mfma_f32_16x16x32_bf16(a[mi], b[ni], acc[mi][ni], 0, 0, 0);
    __syncthreads();
  }

  if (MODE == 0 || MODE == 2) {
#pragma unroll
    for (int mi = 0; mi < 4; ++mi) {
#pragma unroll
      for (int ni = 0; ni < 4; ++ni) {
        int gm = bm + wr + mi * 16 + l4 * 4;
        int gn = bn + wc + ni * 16 + l15;
        float bval = bias[gn];
#pragma unroll
        for (int q = 0; q < 4; ++q)
          Cf[(size_t)(gm + q) * N + gn] = (acc[mi][ni][q] + bval) * scale;
      }
    }
  } else {
    // Fused aggregation. Within this tile all columns share one head h.
    const int h = bn >> 11;  // 2048 cols per head
    float red[4][4][2];
#pragma unroll
    for (int mi = 0; mi < 4; ++mi)
#pragma unroll
      for (int q = 0; q < 4; ++q) {
        red[mi][q][0] = 0.f;
        red[mi][q][1] = 0.f;
      }
#pragma unroll
    for (int mi = 0; mi < 4; ++mi) {
      int gmb = bm + wr + mi * 16 + l4 * 4;
#pragma unroll
      for (int ni = 0; ni < 4; ++ni) {
        int gn = bn + wc + ni * 16 + l15;
        int r = gn & 31;  // rule index = col % 32
        float bval = bias[gn];
        const int g = ni >> 1;  // which of the 2 d-outputs this wave covers
#pragma unroll
        for (int q = 0; q < 4; ++q) {
          float w = attn[(size_t)(gmb + q) * 512 + h * 32 + r];
          red[mi][q][g] += (acc[mi][ni][q] + bval) * w;
        }
      }
    }
    // reduce over the 16 column-lanes (l15) -> full sum over 32 rules
#pragma unroll
    for (int mi = 0; mi < 4; ++mi)
#pragma unroll
      for (int q = 0; q < 4; ++q)
#pragma unroll
        for (int g = 0; g < 2; ++g) {
          float v = red[mi][q][g];
          for (int mask = 1; mask < 16; mask <<= 1) v += __shfl_xor(v, mask);
          red[mi][q][g] = v * scale;
        }
    if (l15 == 0) {
      int dbase = ((bn & 2047) + wc) >> 5;  // global d of g==0
#pragma unroll
      for (int mi = 0; mi < 4; ++mi) {
        int gm = bm + wr + mi * 16 + l4 * 4;
#pragma unroll
        for (int q = 0; q < 4; ++q) {
          int m = gm + q;
          int b = m >> 10, s = m & 1023;
          size_t base = (((size_t)(b * 16 + h)) * 1024 + s) * 64;
          X[base + dbase] = f32_to_bf16_rne(red[mi][q][0]);
          X[base + dbase + 1] = f32_to_bf16_rne(red[mi][q][1]);
        }
      }
    }
  }
}

extern "C" void kernel_launch(void* const* d_in, const int* in_sizes, int n_in, void* d_out,
                              int out_size, void* d_ws, size_t ws_size, hipStream_t stream) {
  const float* query = (const float*)d_in[0];
  // d_in[1] = key (unused by the module's forward)
  const float* value = (const float*)d_in[2];
  const float* rk = (const float*)d_in[3];
  const float* rw = (const float*)d_in[4];
  const float* Wq = (const float*)d_in[5];
  const float* bq = (const float*)d_in[6];
  const float* Wv = (const float*)d_in[7];
  const float* bv = (const float*)d_in[8];
  const float* Wo = (const float*)d_in[9];
  const float* bo = (const float*)d_in[10];
  float* out = (float*)d_out;

  const float scale = 0.125f;  // D^-0.5, D=64

  char* p = (char*)d_ws;
  unsigned short* Wv_b = (unsigned short*)p; p += (size_t)33554432 * 2;  // 64 MB
  unsigned short* Aq_b = (unsigned short*)p; p += (size_t)2097152 * 2;   // query bf16
  unsigned short* Av_b = (unsigned short*)p; p += (size_t)2097152 * 2;   // value bf16
  unsigned short* Wq_b = (unsigned short*)p; p += (size_t)1048576 * 2;
  unsigned short* Wo_b = (unsigned short*)p; p += (size_t)1048576 * 2;
  float* qf = (float*)p;           p += (size_t)2097152 * 4;             // q f32 (scaled)
  float* attn = (float*)p;         p += (size_t)1048576 * 4;             // (M,H,R)
  unsigned short* X = (unsigned short*)p;                                 // (B,H,S,D) bf16

  // f32 -> bf16 conversions
  cvt_f32_to_bf16<<<16384, 256, 0, stream>>>(Wv, Wv_b, 4194304);
  cvt_f32_to_bf16<<<1024, 256, 0, stream>>>(query, Aq_b, 262144);
  cvt_f32_to_bf16<<<1024, 256, 0, stream>>>(value, Av_b, 262144);
  cvt_f32_to_bf16<<<512, 256, 0, stream>>>(Wq, Wq_b, 131072);
  cvt_f32_to_bf16<<<512, 256, 0, stream>>>(Wo, Wo_b, 131072);

  // GEMM1: qf = (query @ Wq^T + bq) * scale   (2048 x 1024)
  gemm_bt<0><<<dim3(8, 16), 256, 0, stream>>>(Aq_b, Wq_b, bq, scale, 2048, 1024, 1024, qf,
                                              nullptr, nullptr);
  // fuzzy membership + softmax -> attn
  fuzzy_softmax_k<<<4096, 256, 0, stream>>>(qf, rk, rw, attn);
  // GEMM2 fused: X[b,h,s,d] = scale * sum_r attn * (value @ Wv^T + bv)
  gemm_bt<1><<<dim3(256, 16), 256, 0, stream>>>(Av_b, Wv_b, bv, scale, 2048, 32768, 1024,
                                                nullptr, attn, X);
  // GEMM3: out = X @ Wo^T + bo   (X's (B,H,S,D) layout == the reference's head-major flatten)
  gemm_bt<2><<<dim3(8, 16), 256, 0, stream>>>(X, Wo_b, bo, 1.0f, 2048, 1024, 1024, out,
                                              nullptr, nullptr);
}

// Round 2
// 332.302 us; speedup vs baseline: 1.1949x; 1.1949x over previous
//
#include <hip/hip_runtime.h>
#include <hip/hip_bf16.h>
#include <cstdint>

typedef float f32x4 __attribute__((ext_vector_type(4)));
typedef short bf16x8 __attribute__((ext_vector_type(8)));

__device__ __forceinline__ unsigned short f32_to_bf16_rne(float f) {
  unsigned int u = __float_as_uint(f);
  return (unsigned short)((u + 0x7FFFu + ((u >> 16) & 1u)) >> 16);
}

#define GLOAD_LDS16(gptr, lptr)                                                             \
  __builtin_amdgcn_global_load_lds((const __attribute__((address_space(1))) unsigned int*)(gptr), \
                                   (__attribute__((address_space(3))) unsigned int*)(lptr), 16, 0, 0)

// ---------------- fused f32 -> bf16 for all 5 operands (8 elems / thread) ----------------
__global__ __launch_bounds__(256) void cvt_all(const float* __restrict__ wv,
                                               const float* __restrict__ q,
                                               const float* __restrict__ v,
                                               const float* __restrict__ wq,
                                               const float* __restrict__ wo,
                                               unsigned short* __restrict__ wvb,
                                               unsigned short* __restrict__ qb,
                                               unsigned short* __restrict__ vb,
                                               unsigned short* __restrict__ wqb,
                                               unsigned short* __restrict__ wob) {
  int i = blockIdx.x * 256 + threadIdx.x;  // chunk of 8 floats
  const float* src;
  unsigned short* dst;
  int off;
  if (i < 4194304)      { src = wv; dst = wvb; off = i; }
  else if (i < 4456448) { src = q;  dst = qb;  off = i - 4194304; }
  else if (i < 4718592) { src = v;  dst = vb;  off = i - 4456448; }
  else if (i < 4849664) { src = wq; dst = wqb; off = i - 4718592; }
  else                  { src = wo; dst = wob; off = i - 4849664; }
  const float4* s = (const float4*)src;
  float4 a = s[2 * off], b = s[2 * off + 1];
  uint4 o;
  o.x = (unsigned)f32_to_bf16_rne(a.x) | ((unsigned)f32_to_bf16_rne(a.y) << 16);
  o.y = (unsigned)f32_to_bf16_rne(a.z) | ((unsigned)f32_to_bf16_rne(a.w) << 16);
  o.z = (unsigned)f32_to_bf16_rne(b.x) | ((unsigned)f32_to_bf16_rne(b.y) << 16);
  o.w = (unsigned)f32_to_bf16_rne(b.z) | ((unsigned)f32_to_bf16_rne(b.w) << 16);
  ((uint4*)dst)[off] = o;
}

// ---------------- fuzzy membership + softmax over rules ----------------
__global__ __launch_bounds__(256) void fuzzy_softmax_k(const float* __restrict__ qf,
                                                       const float* __restrict__ rk,
                                                       const float* __restrict__ rw,
                                                       float* __restrict__ attn) {
  int p = blockIdx.x * 8 + (threadIdx.x >> 5);
  int r = threadIdx.x & 31;
  int m = p >> 4;
  int h = p & 15;
  const float* qrow = qf + (size_t)m * 1024 + h * 64;
  const float* krow = rk + (size_t)(h * 32 + r) * 64;
  const float* wrow = rw + (size_t)(h * 32 + r) * 64;
  float acc = 0.f;
#pragma unroll
  for (int d0 = 0; d0 < 64; d0 += 4) {
    float4 qv = *(const float4*)(qrow + d0);
    float4 kv = *(const float4*)(krow + d0);
    float4 wv = *(const float4*)(wrow + d0);
    float t;
    t = fabsf(qv.x - kv.x) / wv.x; acc += t * t;
    t = fabsf(qv.y - kv.y) / wv.y; acc += t * t;
    t = fabsf(qv.z - kv.z) / wv.z; acc += t * t;
    t = fabsf(qv.w - kv.w) / wv.w; acc += t * t;
  }
  float z = -0.5f * (acc * (1.0f / 64.0f));
  float mx = z;
#pragma unroll
  for (int mask = 16; mask >= 1; mask >>= 1) mx = fmaxf(mx, __shfl_xor(mx, mask));
  float e = __expf(z - mx);
  float s = e;
#pragma unroll
  for (int mask = 16; mask >= 1; mask >>= 1) s += __shfl_xor(s, mask);
  attn[(size_t)m * 512 + h * 32 + r] = e / s;
}

// ---------------- small bf16 GEMM (128x128 tile): C = (A @ W^T + bias) * scale ----------------
__global__ __launch_bounds__(256) void gemm_bt(const unsigned short* __restrict__ A,
                                               const unsigned short* __restrict__ W,
                                               const float* __restrict__ bias, float scale,
                                               int M, int N, int K, float* __restrict__ Cf) {
  constexpr int BM = 128, BN = 128, BK = 32;
  __shared__ unsigned short As[2][BM * BK];
  __shared__ unsigned short Bs[2][BN * BK];
  const int tid = threadIdx.x;
  const int wid = tid >> 6;
  const int lane = tid & 63;
  const int l15 = lane & 15;
  const int l4 = lane >> 4;
  const int bm = blockIdx.y * BM;
  const int bn = blockIdx.x * BN;
  const int wr = (wid >> 1) * 64;
  const int wc = (wid & 1) * 64;

  f32x4 acc[4][4];
#pragma unroll
  for (int i = 0; i < 4; ++i)
#pragma unroll
    for (int j = 0; j < 4; ++j) acc[i][j] = (f32x4){0.f, 0.f, 0.f, 0.f};

  const int nk = K / BK;
  auto stage = [&](int buf, int kt) {
#pragma unroll
    for (int i = 0; i < 2; ++i) {
      int c = (wid * 2 + i) * 64 + lane;
      const unsigned short* ga = A + (size_t)(bm + (c >> 2)) * K + kt * BK + (c & 3) * 8;
      GLOAD_LDS16(ga, &As[buf][(wid * 2 + i) * 512]);
      const unsigned short* gb = W + (size_t)(bn + (c >> 2)) * K + kt * BK + (c & 3) * 8;
      GLOAD_LDS16(gb, &Bs[buf][(wid * 2 + i) * 512]);
    }
  };

  stage(0, 0);
  __syncthreads();

  for (int kt = 0; kt < nk; ++kt) {
    const int cur = kt & 1;
    if (kt + 1 < nk) stage(cur ^ 1, kt + 1);
    bf16x8 a[4], b[4];
    const int koff = l4 * 8;
#pragma unroll
    for (int mi = 0; mi < 4; ++mi)
      a[mi] = *(const bf16x8*)&As[cur][(wr + mi * 16 + l15) * BK + koff];
#pragma unroll
    for (int ni = 0; ni < 4; ++ni)
      b[ni] = *(const bf16x8*)&Bs[cur][(wc + ni * 16 + l15) * BK + koff];
#pragma unroll
    for (int mi = 0; mi < 4; ++mi)
#pragma unroll
      for (int ni = 0; ni < 4; ++ni)
        acc[mi][ni] = __builtin_amdgcn_mfma_f32_16x16x32_bf16(a[mi], b[ni], acc[mi][ni], 0, 0, 0);
    __syncthreads();
  }

#pragma unroll
  for (int mi = 0; mi < 4; ++mi) {
#pragma unroll
    for (int ni = 0; ni < 4; ++ni) {
      int gm = bm + wr + mi * 16 + l4 * 4;
      int gn = bn + wc + ni * 16 + l15;
      float bval = bias[gn];
#pragma unroll
      for (int q = 0; q < 4; ++q)
        Cf[(size_t)(gm + q) * N + gn] = (acc[mi][ni][q] + bval) * scale;
    }
  }
}

// ---------------- GEMM2: 256x256 tile, BK=32, 3-buffer deep pipeline, fused aggregation ----------------
// A: value bf16 (2048 x 1024), W: Wv bf16 (32768 x 1024)
// X[b,h,s,d] = scale * sum_r attn[m,h,r] * (A[m,:]@W[h*2048+d*32+r,:] + bias)
__global__ __launch_bounds__(512, 2) void gemm2_k(const unsigned short* __restrict__ A,
                                                  const unsigned short* __restrict__ W,
                                                  const float* __restrict__ bias, float scale,
                                                  const float* __restrict__ attn,
                                                  unsigned short* __restrict__ X) {
  constexpr int K = 1024;
  constexpr int BK = 32, nk = K / BK;  // 32 K-tiles
  extern __shared__ unsigned short lds[];  // 3 bufs x (A 8192 + B 8192) ushorts = 96 KB
  const int tid = threadIdx.x;
  const int wid = tid >> 6, lane = tid & 63;
  const int l15 = lane & 15, l4 = lane >> 4;
  const int wm = wid >> 2, wn = wid & 3;

  // XCD-aware bijective swizzle (1024 % 8 == 0), column-strip per XCD for B-panel L2 reuse
  int orig = blockIdx.x;
  int swz = (orig & 7) * 128 + (orig >> 3);
  int by = swz & 7;   // 8 row tiles (M=2048)
  int bx = swz >> 3;  // 128 col tiles (N=32768)
  const int bm = by * 256, bn = bx * 256;

  auto stageA = [&](int buf, int kt) {
#pragma unroll
    for (int i = 0; i < 2; ++i) {
      int c = i * 512 + tid;  // 0..1023 chunks of 16B; tile = 256 rows x 4 chunks
      int row = c >> 2, ch = c & 3;
      int sch = ch ^ ((row >> 1) & 3);  // inverse swizzle on the SOURCE (rule #21)
      const unsigned short* g = A + (size_t)(bm + row) * K + kt * BK + sch * 8;
      GLOAD_LDS16(g, lds + buf * 16384 + c * 8);
    }
  };
  auto stageB = [&](int buf, int kt) {
#pragma unroll
    for (int i = 0; i < 2; ++i) {
      int c = i * 512 + tid;
      int row = c >> 2, ch = c & 3;
      int sch = ch ^ ((row >> 1) & 3);
      const unsigned short* g = W + (size_t)(bn + row) * K + kt * BK + sch * 8;
      GLOAD_LDS16(g, lds + buf * 16384 + 8192 + c * 8);
    }
  };

  f32x4 acc[8][4];
#pragma unroll
  for (int i = 0; i < 8; ++i)
#pragma unroll
    for (int j = 0; j < 4; ++j) acc[i][j] = (f32x4){0.f, 0.f, 0.f, 0.f};

  // prologue: stage K-tiles 0 and 1; wait for tile 0 only (counted vmcnt)
  stageA(0, 0); stageB(0, 0);
  stageA(1, 1); stageB(1, 1);
  asm volatile("s_waitcnt vmcnt(4)" ::: "memory");
  __builtin_amdgcn_s_barrier();

  int cur = 0;
  for (int T = 0; T < nk; ++T) {
    const unsigned short* bufA = lds + cur * 16384;
    const unsigned short* bufB = bufA + 8192;
    int stb = cur + 2; if (stb >= 3) stb -= 3;  // buffer of T+2 (last read by T-1: free)
    bf16x8 a[4], b[4];

    // ---- phase 1: read B frags + A frags (rows 0..63 of wave's 128) ----
#pragma unroll
    for (int nf = 0; nf < 4; ++nf) {
      int rl = wn * 64 + nf * 16 + l15;
      int ph = ((rl << 6) + (l4 << 4)) ^ (((rl >> 1) & 3) << 4);
      b[nf] = *(const bf16x8*)((const char*)bufB + ph);
    }
#pragma unroll
    for (int mf = 0; mf < 4; ++mf) {
      int rl = wm * 128 + mf * 16 + l15;
      int ph = ((rl << 6) + (l4 << 4)) ^ (((rl >> 1) & 3) << 4);
      a[mf] = *(const bf16x8*)((const char*)bufA + ph);
    }
    if (T + 2 < nk) stageA(stb, T + 2);
    __builtin_amdgcn_s_barrier();
    asm volatile("s_waitcnt lgkmcnt(0)" ::: "memory");
    __builtin_amdgcn_sched_barrier(0);
    __builtin_amdgcn_s_setprio(1);
#pragma unroll
    for (int mf = 0; mf < 4; ++mf)
#pragma unroll
      for (int nf = 0; nf < 4; ++nf)
        acc[mf][nf] = __builtin_amdgcn_mfma_f32_16x16x32_bf16(a[mf], b[nf], acc[mf][nf], 0, 0, 0);
    __builtin_amdgcn_s_setprio(0);
    __builtin_amdgcn_s_barrier();

    // ---- phase 2: read A frags (rows 64..127); B frags reused from registers ----
#pragma unroll
    for (int mf = 0; mf < 4; ++mf) {
      int rl = wm * 128 + 64 + mf * 16 + l15;
      int ph = ((rl << 6) + (l4 << 4)) ^ (((rl >> 1) & 3) << 4);
      a[mf] = *(const bf16x8*)((const char*)bufA + ph);
    }
    if (T + 2 < nk) {
      stageB(stb, T + 2);
      asm volatile("s_waitcnt vmcnt(4)" ::: "memory");  // T+1 fully landed; T+2 (4 loads) in flight
    } else {
      asm volatile("s_waitcnt vmcnt(0)" ::: "memory");  // tail drain
    }
    __builtin_amdgcn_s_barrier();
    asm volatile("s_waitcnt lgkmcnt(0)" ::: "memory");
    __builtin_amdgcn_sched_barrier(0);
    __builtin_amdgcn_s_setprio(1);
#pragma unroll
    for (int mf = 0; mf < 4; ++mf)
#pragma unroll
      for (int nf = 0; nf < 4; ++nf)
        acc[4 + mf][nf] = __builtin_amdgcn_mfma_f32_16x16x32_bf16(a[mf], b[nf], acc[4 + mf][nf], 0, 0, 0);
    __builtin_amdgcn_s_setprio(0);
    __builtin_amdgcn_s_barrier();

    cur = cur + 1; if (cur >= 3) cur = 0;
  }

  // ---- fused rule-aggregation epilogue (per-mf to bound register pressure) ----
  const int h = bn >> 11;                       // 2048 cols per head
  const int dbase = ((bn & 2047) + wn * 64) >> 5;  // even
#pragma unroll
  for (int mf = 0; mf < 8; ++mf) {
    int gm0 = bm + wm * 128 + mf * 16 + l4 * 4;
    float red[4][2];
#pragma unroll
    for (int q = 0; q < 4; ++q) { red[q][0] = 0.f; red[q][1] = 0.f; }
#pragma unroll
    for (int nf = 0; nf < 4; ++nf) {
      int col = bn + wn * 64 + nf * 16 + l15;
      float bval = bias[col];
      int r = (nf & 1) * 16 + l15;
      int g = nf >> 1;
#pragma unroll
      for (int q = 0; q < 4; ++q) {
        float w = attn[(size_t)(gm0 + q) * 512 + h * 32 + r];
        red[q][g] += (acc[mf][nf][q] + bval) * w;
      }
    }
#pragma unroll
    for (int q = 0; q < 4; ++q)
#pragma unroll
      for (int g = 0; g < 2; ++g) {
        float vv = red[q][g];
        for (int mask = 1; mask < 16; mask <<= 1) vv += __shfl_xor(vv, mask);
        red[q][g] = vv * scale;
      }
    if (l15 == 0) {
#pragma unroll
      for (int q = 0; q < 4; ++q) {
        int m = gm0 + q;
        int bb = m >> 10, s = m & 1023;
        size_t base = (((size_t)(bb * 16 + h)) * 1024 + s) * 64;
        unsigned lo = f32_to_bf16_rne(red[q][0]);
        unsigned hi = f32_to_bf16_rne(red[q][1]);
        ((unsigned*)X)[(base + dbase) >> 1] = lo | (hi << 16);
      }
    }
  }
}

extern "C" void kernel_launch(void* const* d_in, const int* in_sizes, int n_in, void* d_out,
                              int out_size, void* d_ws, size_t ws_size, hipStream_t stream) {
  const float* query = (const float*)d_in[0];
  const float* value = (const float*)d_in[2];
  const float* rk = (const float*)d_in[3];
  const float* rw = (const float*)d_in[4];
  const float* Wq = (const float*)d_in[5];
  const float* bq = (const float*)d_in[6];
  const float* Wv = (const float*)d_in[7];
  const float* bv = (const float*)d_in[8];
  const float* Wo = (const float*)d_in[9];
  const float* bo = (const float*)d_in[10];
  float* out = (float*)d_out;

  const float scale = 0.125f;

  char* p = (char*)d_ws;
  unsigned short* Wv_b = (unsigned short*)p; p += (size_t)33554432 * 2;
  unsigned short* Aq_b = (unsigned short*)p; p += (size_t)2097152 * 2;
  unsigned short* Av_b = (unsigned short*)p; p += (size_t)2097152 * 2;
  unsigned short* Wq_b = (unsigned short*)p; p += (size_t)1048576 * 2;
  unsigned short* Wo_b = (unsigned short*)p; p += (size_t)1048576 * 2;
  float* qf = (float*)p;   p += (size_t)2097152 * 4;
  float* attn = (float*)p; p += (size_t)1048576 * 4;
  unsigned short* X = (unsigned short*)p;

  // one fused conversion pass (4980736 chunks of 8 floats)
  cvt_all<<<19456, 256, 0, stream>>>(Wv, query, value, Wq, Wo, Wv_b, Aq_b, Av_b, Wq_b, Wo_b);

  // GEMM1: qf = (query @ Wq^T + bq) * scale
  gemm_bt<<<dim3(8, 16), 256, 0, stream>>>(Aq_b, Wq_b, bq, scale, 2048, 1024, 1024, qf);
  // fuzzy membership + softmax -> attn
  fuzzy_softmax_k<<<4096, 256, 0, stream>>>(qf, rk, rw, attn);
  // GEMM2 fused (deep-pipelined 256^2)
  hipFuncSetAttribute((const void*)gemm2_k, hipFuncAttributeMaxDynamicSharedMemorySize, 98304);
  gemm2_k<<<1024, 512, 98304, stream>>>(Av_b, Wv_b, bv, scale, attn, X);
  // GEMM3: out = X @ Wo^T + bo
  gemm_bt<<<dim3(8, 16), 256, 0, stream>>>(X, Wo_b, bo, 1.0f, 2048, 1024, 1024, out);
}